// Round 2
// baseline (599.492 us; speedup 1.0000x reference)
//
#include <hip/hip_runtime.h>
#include <stdint.h>

#define NDIM 512
#define CDIM 128
#define MDIM (NDIM*NDIM)   // 262144

typedef unsigned short u16;
typedef __bf16 bf16v8 __attribute__((ext_vector_type(8)));
typedef float f32x4 __attribute__((ext_vector_type(4)));
typedef short s16x4 __attribute__((ext_vector_type(4)));

__device__ __forceinline__ u16 f2bf(float f){
  union { float f; uint32_t u; } v; v.f = f;
  uint32_t u = v.u;
  u += 0x7fffu + ((u >> 16) & 1u);   // round-to-nearest-even
  return (u16)(u >> 16);
}
__device__ __forceinline__ float sigm(float x){
  return __builtin_amdgcn_rcpf(1.0f + __expf(-x));
}
__device__ __forceinline__ f32x4 mfma_bf16(bf16v8 a, bf16v8 b, f32x4 c){
  return __builtin_amdgcn_mfma_f32_16x16x32_bf16(a, b, c, 0, 0, 0);
}

// ---------------------------------------------------------------------------
// K0: pack weights transposed to bf16. wt[d][k], d in [0,768):
//   d<256: w_proj[:,d] ; d<512: w_gate[:,d-256] ; d<640: w_gate_out[:,d-512]
//   d>=640: w_out[:,d-640]  (Wt2 region for K3)
// ---------------------------------------------------------------------------
__global__ void k0_prep(const float* __restrict__ wp, const float* __restrict__ wg,
                        const float* __restrict__ wgo, const float* __restrict__ wo,
                        u16* __restrict__ wt){
  const int d = blockIdx.x, k = threadIdx.x;
  float v;
  if (d < 256)      v = wp[k*256 + d];
  else if (d < 512) v = wg[k*256 + (d-256)];
  else if (d < 640) v = wgo[k*128 + (d-512)];
  else              v = wo[k*128 + (d-640)];
  wt[d*CDIM + k] = f2bf(v);
}

// ---------------------------------------------------------------------------
// K1 (R2 rework): ONE barrier total. Phase 1: 256 threads LN 64 rows -> xs.
// Barrier. Then each wave is fully independent:
//   wave w: rows 32*(w&1)..+32, proj/gate channels [128*(w>>1), +128)
//   8 channel-pair iterations: load weights -> 16 MFMA -> sigm*mask ->
//   per-wave LDS transpose (double-buffered, wave-synchronous, no barrier) ->
//   64B-line coalesced AB store (fire-and-forget, overlaps next iter).
//   Then gate_out: e in [64u, 64u+64), stores sigmoid directly.
// ---------------------------------------------------------------------------
__global__ __launch_bounds__(256) void k1_ln_proj(
    const float* __restrict__ act, const float* __restrict__ mask,
    const float* __restrict__ lns, const float* __restrict__ lno,
    const float* __restrict__ bgo, const u16* __restrict__ wt,
    u16* __restrict__ AB, float* __restrict__ gate)
{
  __shared__ __align__(16) u16 xs[64][136];      // LN output, pitch 272B
  __shared__ __align__(16) u16 pgs[4][2][16][40]; // per-wave [d][m] transpose, dbuf
  const int t = threadIdx.x;
  const int m0 = blockIdx.x * 64;

  { // Phase 1: layernorm, 4 threads per row (unchanged)
    const int r = t >> 2, q = t & 3;
    const float4* rp = (const float4*)(act + (size_t)(m0 + r)*CDIM + q*32);
    float4 v[8];
    #pragma unroll
    for (int i = 0; i < 8; ++i) v[i] = rp[i];
    float s = 0.f, s2 = 0.f;
    #pragma unroll
    for (int i = 0; i < 8; ++i){
      s  += v[i].x + v[i].y + v[i].z + v[i].w;
      s2 += v[i].x*v[i].x + v[i].y*v[i].y + v[i].z*v[i].z + v[i].w*v[i].w;
    }
    s += __shfl_xor(s, 1);  s2 += __shfl_xor(s2, 1);
    s += __shfl_xor(s, 2);  s2 += __shfl_xor(s2, 2);
    const float mean = s * (1.f/128.f);
    const float rstd = rsqrtf(s2 * (1.f/128.f) - mean*mean + 1e-5f);
    const float4* lsp = (const float4*)(lns + q*32);
    const float4* lop = (const float4*)(lno + q*32);
    #pragma unroll
    for (int i = 0; i < 8; ++i){
      const float4 sc = lsp[i], of = lop[i];
      s16x4 pk;
      pk.x = (short)f2bf((v[i].x - mean)*rstd*sc.x + of.x);
      pk.y = (short)f2bf((v[i].y - mean)*rstd*sc.y + of.y);
      pk.z = (short)f2bf((v[i].z - mean)*rstd*sc.z + of.z);
      pk.w = (short)f2bf((v[i].w - mean)*rstd*sc.w + of.w);
      *(s16x4*)&xs[r][q*32 + i*4] = pk;
    }
  }
  __syncthreads();   // the ONLY barrier in this kernel

  const int w = t >> 6, L = t & 63, ln16 = L & 15, quad = L >> 4;
  const int h = w & 1, u = w >> 1;   // row-half, channel-half
  const int rbase = 32*h;            // wave's first local row

  // A fragments: 2 row-subtiles x 4 k-slices (32 VGPRs)
  bf16v8 af[2][4];
  #pragma unroll
  for (int rs = 0; rs < 2; ++rs)
    #pragma unroll
    for (int kk = 0; kk < 4; ++kk)
      af[rs][kk] = *(const bf16v8*)&xs[rbase + rs*16 + ln16][kk*32 + quad*8];

  // mask for this lane's 8 output rows
  const float4 mk0 = *(const float4*)(mask + m0 + rbase +      quad*4);
  const float4 mk1 = *(const float4*)(mask + m0 + rbase + 16 + quad*4);

  const f32x4 zero4 = {0.f,0.f,0.f,0.f};
  const int d2 = L >> 2, mg = L & 3;   // read-back/store lane mapping

  #pragma unroll 2
  for (int pi = 0; pi < 8; ++pi){
    const int dg = 128*u + 16*pi;                 // first channel this iter
    const u16* wpr = wt + (size_t)(dg + ln16)*CDIM + quad*8;
    const u16* wgr = wpr + (size_t)256*CDIM;
    bf16v8 bp[4], bg[4];
    #pragma unroll
    for (int kk = 0; kk < 4; ++kk){
      bp[kk] = *(const bf16v8*)(wpr + kk*32);
      bg[kk] = *(const bf16v8*)(wgr + kk*32);
    }
    f32x4 aP[2] = {zero4, zero4};
    f32x4 aG[2] = {zero4, zero4};
    #pragma unroll
    for (int kk = 0; kk < 4; ++kk)
      #pragma unroll
      for (int rs = 0; rs < 2; ++rs){
        aP[rs] = mfma_bf16(af[rs][kk], bp[kk], aP[rs]);
        aG[rs] = mfma_bf16(af[rs][kk], bg[kk], aG[rs]);
      }
    // epilogue: pg = P*sigm(G)*mask, write [d=ln16][m=16rs+4quad+reg] (8B aligned)
    #pragma unroll
    for (int rs = 0; rs < 2; ++rs){
      const float4 mk = rs ? mk1 : mk0;
      s16x4 pk;
      pk.x = (short)f2bf(aP[rs][0] * sigm(aG[rs][0]) * mk.x);
      pk.y = (short)f2bf(aP[rs][1] * sigm(aG[rs][1]) * mk.y);
      pk.z = (short)f2bf(aP[rs][2] * sigm(aG[rs][2]) * mk.z);
      pk.w = (short)f2bf(aP[rs][3] * sigm(aG[rs][3]) * mk.w);
      *(s16x4*)&pgs[w][pi & 1][ln16][rs*16 + quad*4] = pk;
    }
    // wave-synchronous transpose read (DS ops in-order within a wave; compiler
    // inserts the lgkmcnt wait) then 64B-line coalesced store
    const bf16v8 ov = *(const bf16v8*)&pgs[w][pi & 1][d2][mg*8];
    *(bf16v8*)(AB + (size_t)(dg + d2)*MDIM + m0 + rbase + mg*8) = ov;
  }

  // gate_out: e in [64u, 64u+64), rows rbase..rbase+32
  #pragma unroll 2
  for (int n = 0; n < 4; ++n){
    const int e = 64*u + 16*n + ln16;
    const u16* wr = wt + (size_t)(512 + e)*CDIM + quad*8;
    bf16v8 bb[4];
    #pragma unroll
    for (int kk = 0; kk < 4; ++kk) bb[kk] = *(const bf16v8*)(wr + kk*32);
    f32x4 ag[2] = {zero4, zero4};
    #pragma unroll
    for (int kk = 0; kk < 4; ++kk)
      #pragma unroll
      for (int rs = 0; rs < 2; ++rs)
        ag[rs] = mfma_bf16(af[rs][kk], bb[kk], ag[rs]);
    const float bias = bgo[e];
    #pragma unroll
    for (int rs = 0; rs < 2; ++rs)
      #pragma unroll
      for (int reg = 0; reg < 4; ++reg){
        const int ml = rbase + rs*16 + quad*4 + reg;
        gate[(size_t)(m0 + ml)*CDIM + e] = sigm(ag[rs][reg] + bias);
      }
  }
}

// ---------------------------------------------------------------------------
// K2: per-channel triangle GEMM act2[c] = a[c] @ b[c]^T  (a=AB[2c], b=AB[2c+1])
//     128x128 tile, BK=64, 4 waves * (64x64, 4x4 accs). gemm_bt structure.
// ---------------------------------------------------------------------------
__global__ __launch_bounds__(256) void k2_tri(const u16* __restrict__ AB,
                                              u16* __restrict__ act2)
{
  __shared__ __align__(16) u16 As[128][72];
  __shared__ __align__(16) u16 Bs[128][72];
  const int t = threadIdx.x, bid = blockIdx.x;
  const int c  = bid >> 4;
  const int i0 = ((bid >> 2) & 3) * 128;
  const int j0 = (bid & 3) * 128;
  const u16* Ag = AB + (size_t)(2*c)*MDIM;
  const u16* Bg = AB + (size_t)(2*c + 1)*MDIM;

  const int w = t >> 6, L = t & 63, ln16 = L & 15, quad = L >> 4;
  const int iw = (w & 1)*64, jw = (w >> 1)*64;
  const int r = t >> 1, h = t & 1;   // staging: row r, 64B half h

  const f32x4 zero4 = {0.f,0.f,0.f,0.f};
  f32x4 acc[4][4];
  #pragma unroll
  for (int x = 0; x < 4; ++x)
    #pragma unroll
    for (int y = 0; y < 4; ++y) acc[x][y] = zero4;

  for (int k0 = 0; k0 < NDIM; k0 += 64){
    const u16* ga = Ag + (size_t)(i0 + r)*NDIM + k0 + h*32;
    const u16* gb = Bg + (size_t)(j0 + r)*NDIM + k0 + h*32;
    bf16v8 sa[4], sb[4];
    #pragma unroll
    for (int x = 0; x < 4; ++x){
      sa[x] = *(const bf16v8*)(ga + x*8);
      sb[x] = *(const bf16v8*)(gb + x*8);
    }
    __syncthreads();                // prior iter's LDS reads complete
    #pragma unroll
    for (int x = 0; x < 4; ++x){
      *(bf16v8*)&As[r][h*32 + x*8] = sa[x];
      *(bf16v8*)&Bs[r][h*32 + x*8] = sb[x];
    }
    __syncthreads();
    #pragma unroll
    for (int kk = 0; kk < 2; ++kk){
      bf16v8 ar[4], br[4];
      #pragma unroll
      for (int x = 0; x < 4; ++x) ar[x] = *(const bf16v8*)&As[iw + x*16 + ln16][kk*32 + quad*8];
      #pragma unroll
      for (int y = 0; y < 4; ++y) br[y] = *(const bf16v8*)&Bs[jw + y*16 + ln16][kk*32 + quad*8];
      #pragma unroll
      for (int x = 0; x < 4; ++x)
        #pragma unroll
        for (int y = 0; y < 4; ++y)
          acc[x][y] = mfma_bf16(ar[x], br[y], acc[x][y]);
    }
  }

  u16* op = act2 + (size_t)c*MDIM;
  #pragma unroll
  for (int x = 0; x < 4; ++x)
    #pragma unroll
    for (int y = 0; y < 4; ++y)
      #pragma unroll
      for (int reg = 0; reg < 4; ++reg){
        const int il = iw + x*16 + quad*4 + reg;
        const int jl = jw + y*16 + ln16;
        op[(size_t)(i0 + il)*NDIM + j0 + jl] = f2bf(acc[x][y][reg]);
      }
}

// ---------------------------------------------------------------------------
// K3: per (i, 64 j's): gather act2[:,i,j] (transposed tile), channel-LN over c,
//     MFMA with w_out^T + b_out, multiply by gate (in d_out), store fp32.
// ---------------------------------------------------------------------------
__global__ __launch_bounds__(256) void k3_out(
    const u16* __restrict__ act2, const u16* __restrict__ wt2,
    const float* __restrict__ cns, const float* __restrict__ cno,
    const float* __restrict__ bo, float* __restrict__ out)
{
  __shared__ __align__(16) float vs[128][65];    // [c][jj]
  __shared__ __align__(16) u16 xs2[64][136];     // [jj][c] normalized bf16
  __shared__ float csh[128], coh[128];
  const int t = threadIdx.x;
  const int i  = blockIdx.x >> 3;
  const int j0 = (blockIdx.x & 7)*64;
  if (t < 128){ csh[t] = cns[t]; coh[t] = cno[t]; }

  { // load transposed tile
    const int cc = t >> 1, h = t & 1;
    const u16* g = act2 + (size_t)cc*MDIM + (size_t)i*NDIM + j0 + h*32;
    #pragma unroll
    for (int x = 0; x < 4; ++x){
      bf16v8 uv = *(const bf16v8*)(g + x*8);
      #pragma unroll
      for (int e = 0; e < 8; ++e) vs[cc][h*32 + x*8 + e] = (float)uv[e];
    }
  }
  __syncthreads();
  { // stats over c per jj (4 threads/jj, c interleaved by q to dodge banks)
    const int jj = t >> 2, q = t & 3;
    float s = 0.f, s2 = 0.f;
    #pragma unroll
    for (int ci = 0; ci < 32; ++ci){
      const float v = vs[4*ci + q][jj];
      s += v; s2 += v*v;
    }
    s += __shfl_xor(s,1); s2 += __shfl_xor(s2,1);
    s += __shfl_xor(s,2); s2 += __shfl_xor(s2,2);
    const float mean = s*(1.f/128.f);
    const float rstd = rsqrtf(s2*(1.f/128.f) - mean*mean + 1e-5f);
    #pragma unroll
    for (int ci = 0; ci < 32; ++ci){
      const int cc = 4*ci + q;
      xs2[jj][cc] = f2bf((vs[cc][jj] - mean)*rstd*csh[cc] + coh[cc]);
    }
  }
  __syncthreads();

  const int w = t >> 6, L = t & 63, ln16 = L & 15, quad = L >> 4;
  bf16v8 af[4];
  #pragma unroll
  for (int kk = 0; kk < 4; ++kk)
    af[kk] = *(const bf16v8*)&xs2[w*16 + ln16][kk*32 + quad*8];
  const f32x4 zero4 = {0.f,0.f,0.f,0.f};
  #pragma unroll
  for (int n = 0; n < 8; ++n){
    const u16* wr = wt2 + (size_t)(n*16 + ln16)*CDIM + quad*8;
    bf16v8 bb[4];
    #pragma unroll
    for (int kk = 0; kk < 4; ++kk) bb[kk] = *(const bf16v8*)(wr + kk*32);
    f32x4 ac = zero4;
    #pragma unroll
    for (int kk = 0; kk < 4; ++kk) ac = mfma_bf16(af[kk], bb[kk], ac);
    const int e = n*16 + ln16;
    const float bias = bo[e];
    #pragma unroll
    for (int reg = 0; reg < 4; ++reg){
      const int jl = w*16 + quad*4 + reg;
      const size_t idx = ((size_t)i*NDIM + j0 + jl)*(size_t)CDIM + e;
      out[idx] = (ac[reg] + bias) * out[idx];   // gate was staged here by K1
    }
  }
}

// ---------------------------------------------------------------------------
extern "C" void kernel_launch(void* const* d_in, const int* in_sizes, int n_in,
                              void* d_out, int out_size, void* d_ws, size_t ws_size,
                              hipStream_t stream)
{
  const float* act = (const float*)d_in[0];
  const float* msk = (const float*)d_in[1];
  const float* lns = (const float*)d_in[2];
  const float* lno = (const float*)d_in[3];
  const float* wp  = (const float*)d_in[4];
  const float* wg  = (const float*)d_in[5];
  const float* cns = (const float*)d_in[6];
  const float* cno = (const float*)d_in[7];
  const float* wo  = (const float*)d_in[8];
  const float* bo  = (const float*)d_in[9];
  const float* wgo = (const float*)d_in[10];
  const float* bgo = (const float*)d_in[11];
  float* out = (float*)d_out;

  // ws layout: AB (256*M bf16, 128 MiB) | ACT2 (128*M bf16, 64 MiB) | WT (768*128 bf16)
  u16* AB   = (u16*)d_ws;
  u16* ACT2 = AB + (size_t)256*MDIM;
  u16* WT   = ACT2 + (size_t)128*MDIM;

  k0_prep   <<<dim3(768),  dim3(128), 0, stream>>>(wp, wg, wgo, wo, WT);
  k1_ln_proj<<<dim3(4096), dim3(256), 0, stream>>>(act, msk, lns, lno, bgo, WT, AB, out);
  k2_tri    <<<dim3(2048), dim3(256), 0, stream>>>(AB, ACT2);
  k3_out    <<<dim3(4096), dim3(256), 0, stream>>>(ACT2, WT + 640*CDIM, cns, cno, bo, out);
}

// Round 4
// 564.411 us; speedup vs baseline: 1.0622x; 1.0622x over previous
//
#include <hip/hip_runtime.h>
#include <stdint.h>

#define NDIM 512
#define CDIM 128
#define MDIM (NDIM*NDIM)   // 262144

typedef unsigned short u16;
typedef __bf16 bf16v8 __attribute__((ext_vector_type(8)));
typedef float f32x4 __attribute__((ext_vector_type(4)));
typedef short s16x4 __attribute__((ext_vector_type(4)));

__device__ __forceinline__ u16 f2bf(float f){
  union { float f; uint32_t u; } v; v.f = f;
  uint32_t u = v.u;
  u += 0x7fffu + ((u >> 16) & 1u);   // round-to-nearest-even
  return (u16)(u >> 16);
}
__device__ __forceinline__ float bf2f(u16 h){
  union { uint32_t u; float f; } v; v.u = ((uint32_t)h) << 16;
  return v.f;
}
__device__ __forceinline__ float sigm(float x){
  return __builtin_amdgcn_rcpf(1.0f + __expf(-x));
}
__device__ __forceinline__ f32x4 mfma_bf16(bf16v8 a, bf16v8 b, f32x4 c){
  return __builtin_amdgcn_mfma_f32_16x16x32_bf16(a, b, c, 0, 0, 0);
}

// ---------------------------------------------------------------------------
// K0: pack weights transposed to bf16. wt[d][k], d in [0,768):
//   d<256: w_proj[:,d] ; d<512: w_gate[:,d-256] ; d<640: w_gate_out[:,d-512]
//   d>=640: w_out[:,d-640]
// ---------------------------------------------------------------------------
__global__ void k0_prep(const float* __restrict__ wp, const float* __restrict__ wg,
                        const float* __restrict__ wgo, const float* __restrict__ wo,
                        u16* __restrict__ wt){
  const int d = blockIdx.x, k = threadIdx.x;
  float v;
  if (d < 256)      v = wp[k*256 + d];
  else if (d < 512) v = wg[k*256 + (d-256)];
  else if (d < 640) v = wgo[k*128 + (d-512)];
  else              v = wo[k*128 + (d-640)];
  wt[d*CDIM + k] = f2bf(v);
}

// ---------------------------------------------------------------------------
// K1: R0 structure, gate_out phase REMOVED (gate recomputed fused in K3).
// per 64 rows: LN(fp32) -> x(bf16,LDS) -> MFMA x@[w_proj|w_gate]
// -> pg = p*sigmoid(g)*mask -> LDS transpose -> AB[d][m] channel-major.
// ---------------------------------------------------------------------------
__global__ __launch_bounds__(256) void k1_ln_proj(
    const float* __restrict__ act, const float* __restrict__ mask,
    const float* __restrict__ lns, const float* __restrict__ lno,
    const u16* __restrict__ wt, u16* __restrict__ AB)
{
  __shared__ __align__(16) u16 xs[64][136];    // pitch 272B: 2-way bank alias (free)
  __shared__ __align__(16) u16 pgs[256][72];   // [d][m], pitch 144B
  __shared__ float msk[64];
  const int t = threadIdx.x;
  const int m0 = blockIdx.x * 64;

  { // Phase 1: layernorm, 4 threads per row
    const int r = t >> 2, q = t & 3;
    const float4* rp = (const float4*)(act + (size_t)(m0 + r)*CDIM + q*32);
    float4 v[8];
    #pragma unroll
    for (int i = 0; i < 8; ++i) v[i] = rp[i];
    float s = 0.f, s2 = 0.f;
    #pragma unroll
    for (int i = 0; i < 8; ++i){
      s  += v[i].x + v[i].y + v[i].z + v[i].w;
      s2 += v[i].x*v[i].x + v[i].y*v[i].y + v[i].z*v[i].z + v[i].w*v[i].w;
    }
    s += __shfl_xor(s, 1);  s2 += __shfl_xor(s2, 1);
    s += __shfl_xor(s, 2);  s2 += __shfl_xor(s2, 2);
    const float mean = s * (1.f/128.f);
    const float rstd = rsqrtf(s2 * (1.f/128.f) - mean*mean + 1e-5f);
    const float4* lsp = (const float4*)(lns + q*32);
    const float4* lop = (const float4*)(lno + q*32);
    #pragma unroll
    for (int i = 0; i < 8; ++i){
      const float4 sc = lsp[i], of = lop[i];
      s16x4 pk;
      pk.x = (short)f2bf((v[i].x - mean)*rstd*sc.x + of.x);
      pk.y = (short)f2bf((v[i].y - mean)*rstd*sc.y + of.y);
      pk.z = (short)f2bf((v[i].z - mean)*rstd*sc.z + of.z);
      pk.w = (short)f2bf((v[i].w - mean)*rstd*sc.w + of.w);
      *(s16x4*)&xs[r][q*32 + i*4] = pk;
    }
    if (t < 64) msk[t] = mask[m0 + t];
  }
  __syncthreads();

  const int w = t >> 6, L = t & 63, ln16 = L & 15, quad = L >> 4;
  // A fragments: A[m=lane&15][k=quad*8+j], rows = x rows
  bf16v8 af[4][4];
  #pragma unroll
  for (int rs = 0; rs < 4; ++rs)
    #pragma unroll
    for (int kk = 0; kk < 4; ++kk)
      af[rs][kk] = *(const bf16v8*)&xs[rs*16 + ln16][kk*32 + quad*8];

  const f32x4 zero4 = {0.f,0.f,0.f,0.f};
  // proj/gate pairs: wave w owns d-cols [64w, 64w+64)
  #pragma unroll
  for (int pp = 0; pp < 4; ++pp){
    const int p = w*4 + pp;
    const u16* wpr = wt + (size_t)(16*p + ln16)*CDIM + quad*8;
    const u16* wgr = wpr + (size_t)256*CDIM;
    bf16v8 bp[4], bg[4];
    #pragma unroll
    for (int kk = 0; kk < 4; ++kk){
      bp[kk] = *(const bf16v8*)(wpr + kk*32);
      bg[kk] = *(const bf16v8*)(wgr + kk*32);
    }
    f32x4 aP[4] = {zero4, zero4, zero4, zero4};
    f32x4 aG[4] = {zero4, zero4, zero4, zero4};
    #pragma unroll
    for (int kk = 0; kk < 4; ++kk)
      #pragma unroll
      for (int rs = 0; rs < 4; ++rs){
        aP[rs] = mfma_bf16(af[rs][kk], bp[kk], aP[rs]);
        aG[rs] = mfma_bf16(af[rs][kk], bg[kk], aG[rs]);
      }
    #pragma unroll
    for (int rs = 0; rs < 4; ++rs)
      #pragma unroll
      for (int reg = 0; reg < 4; ++reg){
        const int ml = rs*16 + quad*4 + reg;          // C/D: row=quad*4+reg
        const float pg = aP[rs][reg] * sigm(aG[rs][reg]) * msk[ml];
        pgs[16*p + ln16][ml] = f2bf(pg);              // C/D: col=lane&15
      }
  }
  __syncthreads();

  // AB store: channel-major, 64 contiguous m per block per channel
  #pragma unroll
  for (int p4 = 0; p4 < 4; ++p4){
    const int d = p4*64 + (t >> 2), q = t & 3;
    u16* dst = AB + (size_t)d*MDIM + m0 + q*16;
    const u16* src = &pgs[d][q*16];
    *(bf16v8*)dst       = *(const bf16v8*)src;
    *(bf16v8*)(dst + 8) = *(const bf16v8*)(src + 8);
  }
}

// ---------------------------------------------------------------------------
// K2: per-channel triangle GEMM act2[c] = a[c] @ b[c]^T  (a=AB[2c], b=AB[2c+1])
//     128x128 tile, BK=64, 4 waves * (64x64, 4x4 accs). gemm_bt structure.
//     XCD-aware bijective swizzle: each XCD owns 16 contiguous channels
//     (the 16 tiles of a channel share its a/b panels -> per-XCD L2 reuse).
// ---------------------------------------------------------------------------
__global__ __launch_bounds__(256) void k2_tri(const u16* __restrict__ AB,
                                              u16* __restrict__ act2)
{
  __shared__ __align__(16) u16 As[128][72];
  __shared__ __align__(16) u16 Bs[128][72];
  const int t = threadIdx.x;
  const int bid = (blockIdx.x & 7)*256 + (blockIdx.x >> 3);   // 2048%8==0: bijective
  const int c  = bid >> 4;
  const int i0 = ((bid >> 2) & 3) * 128;
  const int j0 = (bid & 3) * 128;
  const u16* Ag = AB + (size_t)(2*c)*MDIM;
  const u16* Bg = AB + (size_t)(2*c + 1)*MDIM;

  const int w = t >> 6, L = t & 63, ln16 = L & 15, quad = L >> 4;
  const int iw = (w & 1)*64, jw = (w >> 1)*64;
  const int r = t >> 1, h = t & 1;   // staging: row r, 64B half h

  const f32x4 zero4 = {0.f,0.f,0.f,0.f};
  f32x4 acc[4][4];
  #pragma unroll
  for (int x = 0; x < 4; ++x)
    #pragma unroll
    for (int y = 0; y < 4; ++y) acc[x][y] = zero4;

  for (int k0 = 0; k0 < NDIM; k0 += 64){
    const u16* ga = Ag + (size_t)(i0 + r)*NDIM + k0 + h*32;
    const u16* gb = Bg + (size_t)(j0 + r)*NDIM + k0 + h*32;
    bf16v8 sa[4], sb[4];
    #pragma unroll
    for (int x = 0; x < 4; ++x){
      sa[x] = *(const bf16v8*)(ga + x*8);
      sb[x] = *(const bf16v8*)(gb + x*8);
    }
    __syncthreads();                // prior iter's LDS reads complete
    #pragma unroll
    for (int x = 0; x < 4; ++x){
      *(bf16v8*)&As[r][h*32 + x*8] = sa[x];
      *(bf16v8*)&Bs[r][h*32 + x*8] = sb[x];
    }
    __syncthreads();
    #pragma unroll
    for (int kk = 0; kk < 2; ++kk){
      bf16v8 ar[4], br[4];
      #pragma unroll
      for (int x = 0; x < 4; ++x) ar[x] = *(const bf16v8*)&As[iw + x*16 + ln16][kk*32 + quad*8];
      #pragma unroll
      for (int y = 0; y < 4; ++y) br[y] = *(const bf16v8*)&Bs[jw + y*16 + ln16][kk*32 + quad*8];
      #pragma unroll
      for (int x = 0; x < 4; ++x)
        #pragma unroll
        for (int y = 0; y < 4; ++y)
          acc[x][y] = mfma_bf16(ar[x], br[y], acc[x][y]);
    }
  }

  u16* op = act2 + (size_t)c*MDIM;
  #pragma unroll
  for (int x = 0; x < 4; ++x)
    #pragma unroll
    for (int y = 0; y < 4; ++y)
      #pragma unroll
      for (int reg = 0; reg < 4; ++reg){
        const int il = iw + x*16 + quad*4 + reg;
        const int jl = jw + y*16 + ln16;
        op[(size_t)(i0 + il)*NDIM + j0 + jl] = f2bf(acc[x][y][reg]);
      }
}

// ---------------------------------------------------------------------------
// K3: per (i, 64 j's): gather act2[:,i,j] transposed tile (kept bf16 in LDS),
// channel-LN -> xs2; recompute row-LN(act) for the same 64 rows -> xg
// (identical arithmetic to K1 phase 1); then
// out = (xs2@w_out + b_out) * sigmoid(xg@w_gate_out + bgo)  -- pure store.
// LDS: 18.4 + 17.4 + 17.4 + 1 = 54.2 KB (was 67.5 KB fp32 in R3).
// ---------------------------------------------------------------------------
__global__ __launch_bounds__(256) void k3_out(
    const u16* __restrict__ act2, const u16* __restrict__ wt,
    const float* __restrict__ act,
    const float* __restrict__ lns, const float* __restrict__ lno,
    const float* __restrict__ cns, const float* __restrict__ cno,
    const float* __restrict__ bo, const float* __restrict__ bgo,
    float* __restrict__ out)
{
  __shared__ __align__(16) u16 vs[128][72];      // [c][jj] act2 tile bf16, pitch 144B
  __shared__ __align__(16) u16 xs2[64][136];     // [jj][c] channel-normalized bf16
  __shared__ __align__(16) u16 xg[64][136];      // [jj][c] row-LN(act) bf16
  __shared__ float csh[128], coh[128];
  const int t = threadIdx.x;
  const int i  = blockIdx.x >> 3;
  const int j0 = (blockIdx.x & 7)*64;
  const int m0 = i*NDIM + j0;                    // first output/act row
  if (t < 128){ csh[t] = cns[t]; coh[t] = cno[t]; }

  { // load transposed act2 tile (keep bf16)
    const int cc = t >> 1, h = t & 1;
    const u16* g = act2 + (size_t)cc*MDIM + (size_t)i*NDIM + j0 + h*32;
    #pragma unroll
    for (int x = 0; x < 4; ++x)
      *(bf16v8*)&vs[cc][h*32 + x*8] = *(const bf16v8*)(g + x*8);
  }
  { // row-LN of act for the same 64 rows (identical to K1 phase 1) -> xg
    const int r = t >> 2, q = t & 3;
    const float4* rp = (const float4*)(act + (size_t)(m0 + r)*CDIM + q*32);
    float4 v[8];
    #pragma unroll
    for (int ii = 0; ii < 8; ++ii) v[ii] = rp[ii];
    float s = 0.f, s2 = 0.f;
    #pragma unroll
    for (int ii = 0; ii < 8; ++ii){
      s  += v[ii].x + v[ii].y + v[ii].z + v[ii].w;
      s2 += v[ii].x*v[ii].x + v[ii].y*v[ii].y + v[ii].z*v[ii].z + v[ii].w*v[ii].w;
    }
    s += __shfl_xor(s, 1);  s2 += __shfl_xor(s2, 1);
    s += __shfl_xor(s, 2);  s2 += __shfl_xor(s2, 2);
    const float mean = s * (1.f/128.f);
    const float rstd = rsqrtf(s2 * (1.f/128.f) - mean*mean + 1e-5f);
    const float4* lsp = (const float4*)(lns + q*32);
    const float4* lop = (const float4*)(lno + q*32);
    #pragma unroll
    for (int ii = 0; ii < 8; ++ii){
      const float4 sc = lsp[ii], of = lop[ii];
      s16x4 pk;
      pk.x = (short)f2bf((v[ii].x - mean)*rstd*sc.x + of.x);
      pk.y = (short)f2bf((v[ii].y - mean)*rstd*sc.y + of.y);
      pk.z = (short)f2bf((v[ii].z - mean)*rstd*sc.z + of.z);
      pk.w = (short)f2bf((v[ii].w - mean)*rstd*sc.w + of.w);
      *(s16x4*)&xg[r][q*32 + ii*4] = pk;
    }
  }
  __syncthreads();
  { // channel stats over c per jj (4 threads/jj, c interleaved by q)
    const int jj = t >> 2, q = t & 3;
    float s = 0.f, s2 = 0.f;
    #pragma unroll
    for (int ci = 0; ci < 32; ++ci){
      const float v = bf2f(vs[4*ci + q][jj]);
      s += v; s2 += v*v;
    }
    s += __shfl_xor(s,1); s2 += __shfl_xor(s2,1);
    s += __shfl_xor(s,2); s2 += __shfl_xor(s2,2);
    const float mean = s*(1.f/128.f);
    const float rstd = rsqrtf(s2*(1.f/128.f) - mean*mean + 1e-5f);
    #pragma unroll
    for (int ci = 0; ci < 32; ++ci){
      const int cc = 4*ci + q;
      xs2[jj][cc] = f2bf((bf2f(vs[cc][jj]) - mean)*rstd*csh[cc] + coh[cc]);
    }
  }
  __syncthreads();

  const int w = t >> 6, L = t & 63, ln16 = L & 15, quad = L >> 4;
  bf16v8 af[4], ag[4];
  #pragma unroll
  for (int kk = 0; kk < 4; ++kk){
    af[kk] = *(const bf16v8*)&xs2[w*16 + ln16][kk*32 + quad*8];
    ag[kk] = *(const bf16v8*)&xg [w*16 + ln16][kk*32 + quad*8];
  }
  const f32x4 zero4 = {0.f,0.f,0.f,0.f};
  #pragma unroll
  for (int n = 0; n < 8; ++n){
    const u16* wr  = wt + (size_t)(640 + n*16 + ln16)*CDIM + quad*8;  // w_out
    const u16* wgr = wt + (size_t)(512 + n*16 + ln16)*CDIM + quad*8;  // w_gate_out
    bf16v8 bb[4], bg[4];
    #pragma unroll
    for (int kk = 0; kk < 4; ++kk){
      bb[kk] = *(const bf16v8*)(wr  + kk*32);
      bg[kk] = *(const bf16v8*)(wgr + kk*32);
    }
    f32x4 ao = zero4, agg = zero4;
    #pragma unroll
    for (int kk = 0; kk < 4; ++kk){
      ao  = mfma_bf16(af[kk], bb[kk], ao);
      agg = mfma_bf16(ag[kk], bg[kk], agg);
    }
    const int e = n*16 + ln16;
    const float bias = bo[e], bge = bgo[e];
    #pragma unroll
    for (int reg = 0; reg < 4; ++reg){
      const int jl = w*16 + quad*4 + reg;
      out[((size_t)(m0 + jl))*(size_t)CDIM + e] =
          (ao[reg] + bias) * sigm(agg[reg] + bge);
    }
  }
}

// ---------------------------------------------------------------------------
extern "C" void kernel_launch(void* const* d_in, const int* in_sizes, int n_in,
                              void* d_out, int out_size, void* d_ws, size_t ws_size,
                              hipStream_t stream)
{
  const float* act = (const float*)d_in[0];
  const float* msk = (const float*)d_in[1];
  const float* lns = (const float*)d_in[2];
  const float* lno = (const float*)d_in[3];
  const float* wp  = (const float*)d_in[4];
  const float* wg  = (const float*)d_in[5];
  const float* cns = (const float*)d_in[6];
  const float* cno = (const float*)d_in[7];
  const float* wo  = (const float*)d_in[8];
  const float* bo  = (const float*)d_in[9];
  const float* wgo = (const float*)d_in[10];
  const float* bgo = (const float*)d_in[11];
  float* out = (float*)d_out;

  // ws layout: AB (256*M bf16, 128 MiB) | ACT2 (128*M bf16, 64 MiB) | WT (768*128 bf16)
  u16* AB   = (u16*)d_ws;
  u16* ACT2 = AB + (size_t)256*MDIM;
  u16* WT   = ACT2 + (size_t)128*MDIM;

  k0_prep   <<<dim3(768),  dim3(128), 0, stream>>>(wp, wg, wgo, wo, WT);
  k1_ln_proj<<<dim3(4096), dim3(256), 0, stream>>>(act, msk, lns, lno, WT, AB);
  k2_tri    <<<dim3(2048), dim3(256), 0, stream>>>(AB, ACT2);
  k3_out    <<<dim3(4096), dim3(256), 0, stream>>>(ACT2, WT, act, lns, lno,
                                                   cns, cno, bo, bgo, out);
}

// Round 5
// 558.243 us; speedup vs baseline: 1.0739x; 1.0110x over previous
//
#include <hip/hip_runtime.h>
#include <stdint.h>

#define NDIM 512
#define CDIM 128
#define MDIM (NDIM*NDIM)   // 262144

typedef unsigned short u16;
typedef __bf16 bf16v8 __attribute__((ext_vector_type(8)));
typedef float f32x4 __attribute__((ext_vector_type(4)));
typedef short s16x4 __attribute__((ext_vector_type(4)));

__device__ __forceinline__ u16 f2bf(float f){
  union { float f; uint32_t u; } v; v.f = f;
  uint32_t u = v.u;
  u += 0x7fffu + ((u >> 16) & 1u);   // round-to-nearest-even
  return (u16)(u >> 16);
}
__device__ __forceinline__ float bf2f(u16 h){
  union { uint32_t u; float f; } v; v.u = ((uint32_t)h) << 16;
  return v.f;
}
__device__ __forceinline__ float sigm(float x){
  return __builtin_amdgcn_rcpf(1.0f + __expf(-x));
}
__device__ __forceinline__ f32x4 mfma_bf16(bf16v8 a, bf16v8 b, f32x4 c){
  return __builtin_amdgcn_mfma_f32_16x16x32_bf16(a, b, c, 0, 0, 0);
}

// ---------------------------------------------------------------------------
// K0: pack weights transposed to bf16. wt[d][k], d in [0,768):
//   d<256: w_proj[:,d] ; d<512: w_gate[:,d-256] ; d<640: w_gate_out[:,d-512]
//   d>=640: w_out[:,d-640]
// ---------------------------------------------------------------------------
__global__ void k0_prep(const float* __restrict__ wp, const float* __restrict__ wg,
                        const float* __restrict__ wgo, const float* __restrict__ wo,
                        u16* __restrict__ wt){
  const int d = blockIdx.x, k = threadIdx.x;
  float v;
  if (d < 256)      v = wp[k*256 + d];
  else if (d < 512) v = wg[k*256 + (d-256)];
  else if (d < 640) v = wgo[k*128 + (d-512)];
  else              v = wo[k*128 + (d-640)];
  wt[d*CDIM + k] = f2bf(v);
}

// ---------------------------------------------------------------------------
// K1: R0 structure, no gate phase. Chunked XCD swizzle: the 8 j-blocks of a
// row-panel i are consecutive logical blocks -> same XCD -> the channel-major
// 128-B AB writes of (d,i) aggregate into 1-KB bursts in that XCD's L2.
// ---------------------------------------------------------------------------
__global__ __launch_bounds__(256) void k1_ln_proj(
    const float* __restrict__ act, const float* __restrict__ mask,
    const float* __restrict__ lns, const float* __restrict__ lno,
    const u16* __restrict__ wt, u16* __restrict__ AB)
{
  __shared__ __align__(16) u16 xs[64][136];    // pitch 272B: 2-way bank alias (free)
  __shared__ __align__(16) u16 pgs[256][72];   // [d][m], pitch 144B
  __shared__ float msk[64];
  const int t = threadIdx.x;
  const int blk = ((int)blockIdx.x & 7)*512 + ((int)blockIdx.x >> 3);  // 4096%8==0
  const int m0 = blk * 64;

  { // Phase 1: layernorm, 4 threads per row
    const int r = t >> 2, q = t & 3;
    const float4* rp = (const float4*)(act + (size_t)(m0 + r)*CDIM + q*32);
    float4 v[8];
    #pragma unroll
    for (int i = 0; i < 8; ++i) v[i] = rp[i];
    float s = 0.f, s2 = 0.f;
    #pragma unroll
    for (int i = 0; i < 8; ++i){
      s  += v[i].x + v[i].y + v[i].z + v[i].w;
      s2 += v[i].x*v[i].x + v[i].y*v[i].y + v[i].z*v[i].z + v[i].w*v[i].w;
    }
    s += __shfl_xor(s, 1);  s2 += __shfl_xor(s2, 1);
    s += __shfl_xor(s, 2);  s2 += __shfl_xor(s2, 2);
    const float mean = s * (1.f/128.f);
    const float rstd = rsqrtf(s2 * (1.f/128.f) - mean*mean + 1e-5f);
    const float4* lsp = (const float4*)(lns + q*32);
    const float4* lop = (const float4*)(lno + q*32);
    #pragma unroll
    for (int i = 0; i < 8; ++i){
      const float4 sc = lsp[i], of = lop[i];
      s16x4 pk;
      pk.x = (short)f2bf((v[i].x - mean)*rstd*sc.x + of.x);
      pk.y = (short)f2bf((v[i].y - mean)*rstd*sc.y + of.y);
      pk.z = (short)f2bf((v[i].z - mean)*rstd*sc.z + of.z);
      pk.w = (short)f2bf((v[i].w - mean)*rstd*sc.w + of.w);
      *(s16x4*)&xs[r][q*32 + i*4] = pk;
    }
    if (t < 64) msk[t] = mask[m0 + t];
  }
  __syncthreads();

  const int w = t >> 6, L = t & 63, ln16 = L & 15, quad = L >> 4;
  // A fragments: A[m=lane&15][k=quad*8+j], rows = x rows
  bf16v8 af[4][4];
  #pragma unroll
  for (int rs = 0; rs < 4; ++rs)
    #pragma unroll
    for (int kk = 0; kk < 4; ++kk)
      af[rs][kk] = *(const bf16v8*)&xs[rs*16 + ln16][kk*32 + quad*8];

  const f32x4 zero4 = {0.f,0.f,0.f,0.f};
  // proj/gate pairs: wave w owns d-cols [64w, 64w+64)
  #pragma unroll
  for (int pp = 0; pp < 4; ++pp){
    const int p = w*4 + pp;
    const u16* wpr = wt + (size_t)(16*p + ln16)*CDIM + quad*8;
    const u16* wgr = wpr + (size_t)256*CDIM;
    bf16v8 bp[4], bg[4];
    #pragma unroll
    for (int kk = 0; kk < 4; ++kk){
      bp[kk] = *(const bf16v8*)(wpr + kk*32);
      bg[kk] = *(const bf16v8*)(wgr + kk*32);
    }
    f32x4 aP[4] = {zero4, zero4, zero4, zero4};
    f32x4 aG[4] = {zero4, zero4, zero4, zero4};
    #pragma unroll
    for (int kk = 0; kk < 4; ++kk)
      #pragma unroll
      for (int rs = 0; rs < 4; ++rs){
        aP[rs] = mfma_bf16(af[rs][kk], bp[kk], aP[rs]);
        aG[rs] = mfma_bf16(af[rs][kk], bg[kk], aG[rs]);
      }
    #pragma unroll
    for (int rs = 0; rs < 4; ++rs)
      #pragma unroll
      for (int reg = 0; reg < 4; ++reg){
        const int ml = rs*16 + quad*4 + reg;          // C/D: row=quad*4+reg
        const float pg = aP[rs][reg] * sigm(aG[rs][reg]) * msk[ml];
        pgs[16*p + ln16][ml] = f2bf(pg);              // C/D: col=lane&15
      }
  }
  __syncthreads();

  // AB store: channel-major, 64 contiguous m per block per channel
  #pragma unroll
  for (int p4 = 0; p4 < 4; ++p4){
    const int d = p4*64 + (t >> 2), q = t & 3;
    u16* dst = AB + (size_t)d*MDIM + m0 + q*16;
    const u16* src = &pgs[d][q*16];
    *(bf16v8*)dst       = *(const bf16v8*)src;
    *(bf16v8*)(dst + 8) = *(const bf16v8*)(src + 8);
  }
}

// ---------------------------------------------------------------------------
// K2: per-channel triangle GEMM act2[c] = a[c] @ b[c]^T  (a=AB[2c], b=AB[2c+1])
//     128x128 tile, BK=64, 4 waves * (64x64, 4x4 accs). gemm_bt structure.
//     XCD-aware bijective swizzle: each XCD owns 16 contiguous channels.
// ---------------------------------------------------------------------------
__global__ __launch_bounds__(256) void k2_tri(const u16* __restrict__ AB,
                                              u16* __restrict__ act2)
{
  __shared__ __align__(16) u16 As[128][72];
  __shared__ __align__(16) u16 Bs[128][72];
  const int t = threadIdx.x;
  const int bid = ((int)blockIdx.x & 7)*256 + ((int)blockIdx.x >> 3);  // 2048%8==0
  const int c  = bid >> 4;
  const int i0 = ((bid >> 2) & 3) * 128;
  const int j0 = (bid & 3) * 128;
  const u16* Ag = AB + (size_t)(2*c)*MDIM;
  const u16* Bg = AB + (size_t)(2*c + 1)*MDIM;

  const int w = t >> 6, L = t & 63, ln16 = L & 15, quad = L >> 4;
  const int iw = (w & 1)*64, jw = (w >> 1)*64;
  const int r = t >> 1, h = t & 1;   // staging: row r, 64B half h

  const f32x4 zero4 = {0.f,0.f,0.f,0.f};
  f32x4 acc[4][4];
  #pragma unroll
  for (int x = 0; x < 4; ++x)
    #pragma unroll
    for (int y = 0; y < 4; ++y) acc[x][y] = zero4;

  for (int k0 = 0; k0 < NDIM; k0 += 64){
    const u16* ga = Ag + (size_t)(i0 + r)*NDIM + k0 + h*32;
    const u16* gb = Bg + (size_t)(j0 + r)*NDIM + k0 + h*32;
    bf16v8 sa[4], sb[4];
    #pragma unroll
    for (int x = 0; x < 4; ++x){
      sa[x] = *(const bf16v8*)(ga + x*8);
      sb[x] = *(const bf16v8*)(gb + x*8);
    }
    __syncthreads();                // prior iter's LDS reads complete
    #pragma unroll
    for (int x = 0; x < 4; ++x){
      *(bf16v8*)&As[r][h*32 + x*8] = sa[x];
      *(bf16v8*)&Bs[r][h*32 + x*8] = sb[x];
    }
    __syncthreads();
    #pragma unroll
    for (int kk = 0; kk < 2; ++kk){
      bf16v8 ar[4], br[4];
      #pragma unroll
      for (int x = 0; x < 4; ++x) ar[x] = *(const bf16v8*)&As[iw + x*16 + ln16][kk*32 + quad*8];
      #pragma unroll
      for (int y = 0; y < 4; ++y) br[y] = *(const bf16v8*)&Bs[jw + y*16 + ln16][kk*32 + quad*8];
      #pragma unroll
      for (int x = 0; x < 4; ++x)
        #pragma unroll
        for (int y = 0; y < 4; ++y)
          acc[x][y] = mfma_bf16(ar[x], br[y], acc[x][y]);
    }
  }

  u16* op = act2 + (size_t)c*MDIM;
  #pragma unroll
  for (int x = 0; x < 4; ++x)
    #pragma unroll
    for (int y = 0; y < 4; ++y)
      #pragma unroll
      for (int reg = 0; reg < 4; ++reg){
        const int il = iw + x*16 + quad*4 + reg;
        const int jl = jw + y*16 + ln16;
        op[(size_t)(i0 + il)*NDIM + j0 + jl] = f2bf(acc[x][y][reg]);
      }
}

// ---------------------------------------------------------------------------
// K3 (R5): one barrier, register-resident LNs.
//  - act rows for the gate path load straight to registers (4 lanes/row,
//    shfl_xor(16/32) stats) -> ag fragments. No LDS staging.
//  - act2 transposed gather -> vs (bf16, pitch 74: conflict-free column reads).
//  - after barrier: each lane reads its 32 vs-column values, shfl_xor(16/32)
//    stats, normalizes in regs -> af fragments. No xs2, no stats phase.
//  - MFMA: out = (af@w_out + b_out) * sigmoid(ag@w_gate_out + bgo), pure store.
// LDS 18.9 KB. Chunked XCD swizzle co-locates the 8 j-blocks of row i.
// ---------------------------------------------------------------------------
__global__ __launch_bounds__(256) void k3_out(
    const u16* __restrict__ act2, const u16* __restrict__ wt,
    const float* __restrict__ act,
    const float* __restrict__ lns, const float* __restrict__ lno,
    const float* __restrict__ cns, const float* __restrict__ cno,
    const float* __restrict__ bo, const float* __restrict__ bgo,
    float* __restrict__ out)
{
  __shared__ __align__(16) u16 vs[128*74];       // [c][jj], pitch 74 u16
  const int t = threadIdx.x;
  const int blk = ((int)blockIdx.x & 7)*512 + ((int)blockIdx.x >> 3);  // 4096%8==0
  const int i  = blk >> 3;
  const int j0 = (blk & 7)*64;
  const int m0 = i*NDIM + j0;                    // first output/act row

  const int w = t >> 6, L = t & 63, ln16 = L & 15, quad = L >> 4;

  // ---- issue act row loads early (overlap with gather) ----
  const int arow = m0 + w*16 + ln16;             // this lane's A-row
  float4 av[8];
  #pragma unroll
  for (int kk = 0; kk < 4; ++kk){
    const float* ap = act + (size_t)arow*CDIM + kk*32 + quad*8;
    av[2*kk]   = *(const float4*)(ap);
    av[2*kk+1] = *(const float4*)(ap + 4);
  }

  { // ---- act2 transposed gather -> vs ----
    const int cc = t >> 1, h = t & 1;
    const u16* g = act2 + (size_t)cc*MDIM + (size_t)i*NDIM + j0 + h*32;
    #pragma unroll
    for (int x = 0; x < 4; ++x)
      *(bf16v8*)&vs[cc*74 + h*32 + x*8] = *(const bf16v8*)(g + x*8);
  }

  // ---- row-LN of act in registers -> ag fragments (gate path) ----
  union bfu { bf16v8 v; u16 u[8]; };
  bf16v8 ag[4];
  {
    float s = 0.f, s2 = 0.f;
    #pragma unroll
    for (int q2 = 0; q2 < 8; ++q2){
      s  += av[q2].x + av[q2].y + av[q2].z + av[q2].w;
      s2 += av[q2].x*av[q2].x + av[q2].y*av[q2].y + av[q2].z*av[q2].z + av[q2].w*av[q2].w;
    }
    s += __shfl_xor(s,16); s2 += __shfl_xor(s2,16);
    s += __shfl_xor(s,32); s2 += __shfl_xor(s2,32);
    const float mean = s*(1.f/128.f);
    const float rstd = rsqrtf(s2*(1.f/128.f) - mean*mean + 1e-5f);
    #pragma unroll
    for (int kk = 0; kk < 4; ++kk){
      const float4 sc0 = *(const float4*)(lns + kk*32 + quad*8);
      const float4 sc1 = *(const float4*)(lns + kk*32 + quad*8 + 4);
      const float4 of0 = *(const float4*)(lno + kk*32 + quad*8);
      const float4 of1 = *(const float4*)(lno + kk*32 + quad*8 + 4);
      bfu pk;
      pk.u[0] = f2bf((av[2*kk].x   - mean)*rstd*sc0.x + of0.x);
      pk.u[1] = f2bf((av[2*kk].y   - mean)*rstd*sc0.y + of0.y);
      pk.u[2] = f2bf((av[2*kk].z   - mean)*rstd*sc0.z + of0.z);
      pk.u[3] = f2bf((av[2*kk].w   - mean)*rstd*sc0.w + of0.w);
      pk.u[4] = f2bf((av[2*kk+1].x - mean)*rstd*sc1.x + of1.x);
      pk.u[5] = f2bf((av[2*kk+1].y - mean)*rstd*sc1.y + of1.y);
      pk.u[6] = f2bf((av[2*kk+1].z - mean)*rstd*sc1.z + of1.z);
      pk.u[7] = f2bf((av[2*kk+1].w - mean)*rstd*sc1.w + of1.w);
      ag[kk] = pk.v;
    }
  }
  __syncthreads();

  // ---- column-LN of act2 from vs -> af fragments ----
  bf16v8 af[4];
  {
    const int jj = w*16 + ln16;
    float cv[32];
    float s = 0.f, s2 = 0.f;
    #pragma unroll
    for (int kk = 0; kk < 4; ++kk)
      #pragma unroll
      for (int e = 0; e < 8; ++e){
        const float v = bf2f(vs[(kk*32 + quad*8 + e)*74 + jj]);
        cv[kk*8 + e] = v; s += v; s2 += v*v;
      }
    s += __shfl_xor(s,16); s2 += __shfl_xor(s2,16);
    s += __shfl_xor(s,32); s2 += __shfl_xor(s2,32);
    const float mean = s*(1.f/128.f);
    const float rstd = rsqrtf(s2*(1.f/128.f) - mean*mean + 1e-5f);
    #pragma unroll
    for (int kk = 0; kk < 4; ++kk){
      const float4 sc0 = *(const float4*)(cns + kk*32 + quad*8);
      const float4 sc1 = *(const float4*)(cns + kk*32 + quad*8 + 4);
      const float4 of0 = *(const float4*)(cno + kk*32 + quad*8);
      const float4 of1 = *(const float4*)(cno + kk*32 + quad*8 + 4);
      bfu pk;
      pk.u[0] = f2bf((cv[kk*8+0] - mean)*rstd*sc0.x + of0.x);
      pk.u[1] = f2bf((cv[kk*8+1] - mean)*rstd*sc0.y + of0.y);
      pk.u[2] = f2bf((cv[kk*8+2] - mean)*rstd*sc0.z + of0.z);
      pk.u[3] = f2bf((cv[kk*8+3] - mean)*rstd*sc0.w + of0.w);
      pk.u[4] = f2bf((cv[kk*8+4] - mean)*rstd*sc1.x + of1.x);
      pk.u[5] = f2bf((cv[kk*8+5] - mean)*rstd*sc1.y + of1.y);
      pk.u[6] = f2bf((cv[kk*8+6] - mean)*rstd*sc1.z + of1.z);
      pk.u[7] = f2bf((cv[kk*8+7] - mean)*rstd*sc1.w + of1.w);
      af[kk] = pk.v;
    }
  }

  // ---- MFMA: 8 n-tiles of (w_out | w_gate_out), fused epilogue ----
  const f32x4 zero4 = {0.f,0.f,0.f,0.f};
  #pragma unroll
  for (int n = 0; n < 8; ++n){
    const u16* wr  = wt + (size_t)(640 + n*16 + ln16)*CDIM + quad*8;  // w_out
    const u16* wgr = wt + (size_t)(512 + n*16 + ln16)*CDIM + quad*8;  // w_gate_out
    bf16v8 bb[4], bg[4];
    #pragma unroll
    for (int kk = 0; kk < 4; ++kk){
      bb[kk] = *(const bf16v8*)(wr  + kk*32);
      bg[kk] = *(const bf16v8*)(wgr + kk*32);
    }
    f32x4 ao = zero4, agg = zero4;
    #pragma unroll
    for (int kk = 0; kk < 4; ++kk){
      ao  = mfma_bf16(af[kk], bb[kk], ao);
      agg = mfma_bf16(ag[kk], bg[kk], agg);
    }
    const int e = n*16 + ln16;
    const float bias = bo[e], bge = bgo[e];
    #pragma unroll
    for (int reg = 0; reg < 4; ++reg){
      const int jl = w*16 + quad*4 + reg;
      out[((size_t)(m0 + jl))*(size_t)CDIM + e] =
          (ao[reg] + bias) * sigm(agg[reg] + bge);
    }
  }
}

// ---------------------------------------------------------------------------
extern "C" void kernel_launch(void* const* d_in, const int* in_sizes, int n_in,
                              void* d_out, int out_size, void* d_ws, size_t ws_size,
                              hipStream_t stream)
{
  const float* act = (const float*)d_in[0];
  const float* msk = (const float*)d_in[1];
  const float* lns = (const float*)d_in[2];
  const float* lno = (const float*)d_in[3];
  const float* wp  = (const float*)d_in[4];
  const float* wg  = (const float*)d_in[5];
  const float* cns = (const float*)d_in[6];
  const float* cno = (const float*)d_in[7];
  const float* wo  = (const float*)d_in[8];
  const float* bo  = (const float*)d_in[9];
  const float* wgo = (const float*)d_in[10];
  const float* bgo = (const float*)d_in[11];
  float* out = (float*)d_out;

  // ws layout: AB (256*M bf16, 128 MiB) | ACT2 (128*M bf16, 64 MiB) | WT (768*128 bf16)
  u16* AB   = (u16*)d_ws;
  u16* ACT2 = AB + (size_t)256*MDIM;
  u16* WT   = ACT2 + (size_t)128*MDIM;

  k0_prep   <<<dim3(768),  dim3(128), 0, stream>>>(wp, wg, wgo, wo, WT);
  k1_ln_proj<<<dim3(4096), dim3(256), 0, stream>>>(act, msk, lns, lno, WT, AB);
  k2_tri    <<<dim3(2048), dim3(256), 0, stream>>>(AB, ACT2);
  k3_out    <<<dim3(4096), dim3(256), 0, stream>>>(ACT2, WT, act, lns, lno,
                                                   cns, cno, bo, bgo, out);
}